// Round 11
// baseline (370.463 us; speedup 1.0000x reference)
//
#include <hip/hip_runtime.h>
#include <hip/hip_bf16.h>

#define N_NODES 100000
#define N_EDGES 3200000
#define N_GRAPHS 100
#define DIM 64
#define NCLS 10
#define EPS 0.1f
#define SLOPE 0.01f
#define BUCKET 512
#define BUCKET_SH 9
#define NBKT ((N_NODES + BUCKET - 1) / BUCKET)   // 196 buckets of 512 nodes
#define BIN_CH 8192                               // edges per binning block
#define LDS_PAD 72                                // halves per staged row
#define RO_BLOCKS 200                             // readout blocks

using half8  = __attribute__((ext_vector_type(8))) _Float16;
using half4v = __attribute__((ext_vector_type(4))) _Float16;
using f32x4  = __attribute__((ext_vector_type(4))) float;

__device__ __forceinline__ float lrelu(float v) {
    return v >= 0.f ? v : SLOPE * v;
}

// ======================= CSR build =======================
// per-bucket edge counts: block-local LDS histogram, 1 atomic/bucket/block
__global__ void __launch_bounds__(256) bcount_kernel(const int* __restrict__ dst,
                                                     int* __restrict__ bsize, int E) {
    __shared__ int cnt[NBKT];
    int t = threadIdx.x;
    for (int i = t; i < NBKT; i += 256) cnt[i] = 0;
    __syncthreads();
    int e0 = blockIdx.x * BIN_CH;
    int e1 = e0 + BIN_CH; if (e1 > E) e1 = E;
    for (int e = e0 + t; e < e1; e += 256)
        atomicAdd(&cnt[(unsigned)dst[e] >> BUCKET_SH], 1);
    __syncthreads();
    for (int i = t; i < NBKT; i += 256)
        if (cnt[i]) atomicAdd(&bsize[i], cnt[i]);
}

__global__ void __launch_bounds__(512) tile_scan_kernel(const int* __restrict__ tileSum,
                                                        int* __restrict__ tileBase,
                                                        int* __restrict__ bucketCur,
                                                        int* __restrict__ rowptr, int T) {
    __shared__ int sb[512];
    int t = threadIdx.x;
    int v = (t < T) ? tileSum[t] : 0;
    sb[t] = v;
    __syncthreads();
    for (int off = 1; off < 512; off <<= 1) {
        int u = (t >= off) ? sb[t - off] : 0;
        __syncthreads();
        sb[t] += u;
        __syncthreads();
    }
    if (t < T) {
        int base = sb[t] - v;
        tileBase[t]  = base;
        bucketCur[t] = base;
    }
    if (t == 511) rowptr[N_NODES] = sb[511];  // = E
}

// phase A: LDS-staged block-local bucket sort, then per-wave dense burst
// copy-out (each global write instruction is a coalesced run).
__global__ void __launch_bounds__(256) binA_kernel(const int* __restrict__ src,
                                                   const int* __restrict__ dst,
                                                   int* __restrict__ bucketCur,
                                                   int* __restrict__ ssrcEnc, int E) {
    __shared__ int ebuf[BIN_CH];          // 32 KB staged, bucket-sorted
    __shared__ int cnt[NBKT];
    __shared__ int lbase[NBKT];
    __shared__ int wbase[NBKT];
    __shared__ int lcur[NBKT];
    __shared__ int sscan[256];
    const int t = threadIdx.x, wave = t >> 6, lane = t & 63;
    for (int i = t; i < NBKT; i += 256) cnt[i] = 0;
    __syncthreads();
    int e0 = blockIdx.x * BIN_CH;
    int e1 = e0 + BIN_CH; if (e1 > E) e1 = E;
    for (int e = e0 + t; e < e1; e += 256)
        atomicAdd(&cnt[(unsigned)dst[e] >> BUCKET_SH], 1);
    __syncthreads();
    // local exclusive scan of cnt (NBKT <= 256)
    int v = (t < NBKT) ? cnt[t] : 0;
    sscan[t] = v;
    __syncthreads();
    for (int off = 1; off < 256; off <<= 1) {
        int u = (t >= off) ? sscan[t - off] : 0;
        __syncthreads();
        sscan[t] += u;
        __syncthreads();
    }
    if (t < NBKT) {
        int lb = sscan[t] - v;
        lbase[t] = lb;
        lcur[t]  = lb;
        wbase[t] = v ? atomicAdd(&bucketCur[t], v) : 0;
    }
    __syncthreads();
    // scatter into LDS, bucket-sorted
    for (int e = e0 + t; e < e1; e += 256) {
        int d = dst[e];
        int b = (unsigned)d >> BUCKET_SH;
        int p = atomicAdd(&lcur[b], 1);
        ebuf[p] = (src[e] << BUCKET_SH) | (d & (BUCKET - 1));
    }
    __syncthreads();
    // dense copy-out: wave per bucket, lanes sweep the run
    for (int b = wave; b < NBKT; b += 4) {
        int c = cnt[b], lb = lbase[b], wb = wbase[b];
        for (int k = lane; k < c; k += 64)
            ssrcEnc[wb + k] = ebuf[lb + k];
    }
}

// phase B: per bucket (512 nodes) — count, scan -> rowptr, scatter ssrc.
// write window == read slice, L2-resident for the block's lifetime.
__global__ void __launch_bounds__(512) binB_kernel(const int* __restrict__ ssrcEnc,
                                                   const int* __restrict__ tileBase,
                                                   int* __restrict__ rowptr,
                                                   int* __restrict__ ssrc, int E, int NB) {
    __shared__ int cnt[BUCKET];
    __shared__ int sb[BUCKET];
    __shared__ int cur[BUCKET];
    int b = blockIdx.x, t = threadIdx.x;
    cnt[t] = 0;
    __syncthreads();
    int base = tileBase[b];
    int endI = (b + 1 < NB) ? tileBase[b + 1] : E;
    for (int i = base + t; i < endI; i += 512)
        atomicAdd(&cnt[ssrcEnc[i] & (BUCKET - 1)], 1);
    __syncthreads();
    int v = cnt[t];
    sb[t] = v;
    __syncthreads();
    for (int off = 1; off < 512; off <<= 1) {
        int u = (t >= off) ? sb[t - off] : 0;
        __syncthreads();
        sb[t] += u;
        __syncthreads();
    }
    int node0 = b * BUCKET;
    int nn = N_NODES - node0; if (nn > BUCKET) nn = BUCKET;
    if (t < nn) {
        int p = base + sb[t] - v;   // exclusive
        rowptr[node0 + t] = p;
        cur[t] = p;
    }
    __syncthreads();
    for (int i = base + t; i < endI; i += 512) {
        int enc = ssrcEnc[i];
        int p = atomicAdd(&cur[enc & (BUCKET - 1)], 1);
        ssrc[p] = enc >> BUCKET_SH;
    }
}

// ======================= fp32 -> fp16 conversion =======================
__global__ void __launch_bounds__(256) cvt_kernel(const float* __restrict__ x,
                                                  _Float16* __restrict__ H, int n4) {
    int i = blockIdx.x * 256 + threadIdx.x;
    if (i < n4) {
        float4 v = ((const float4*)x)[i];
        half4v h;
        h[0] = (_Float16)v.x; h[1] = (_Float16)v.y;
        h[2] = (_Float16)v.z; h[3] = (_Float16)v.w;
        ((half4v*)H)[i] = h;
    }
}

// weights -> fp16 B-fragment layout for mfma_f32_16x16x32_f16
__global__ void __launch_bounds__(256) wcvt_kernel(const float* __restrict__ W0a,
                                                   const float* __restrict__ W0b,
                                                   const float* __restrict__ Ws1,
                                                   const float* __restrict__ Ws2,
                                                   _Float16* __restrict__ wfrag) {
    int f = blockIdx.x * 256 + threadIdx.x;
    if (f >= 6 * 4096) return;
    int i = f & 7, lane = (f >> 3) & 63, c = (f >> 9) & 3, k0 = (f >> 11) & 1, mat = f >> 12;
    int k = 32 * k0 + (lane >> 4) * 8 + i;
    int n = 16 * c + (lane & 15);
    const float* Wsrc;
    switch (mat) {
        case 0: Wsrc = W0a;        break;
        case 1: Wsrc = W0b;        break;
        case 2: Wsrc = Ws1;        break;
        case 3: Wsrc = Ws2;        break;
        case 4: Wsrc = Ws1 + 4096; break;
        default: Wsrc = Ws2 + 4096; break;
    }
    wfrag[f] = (_Float16)Wsrc[k * DIM + n];
}

// ======================= pure gather (max occupancy, no LDS) ============
// aggH OWNS the self term. 8 lanes/edge; 4 rows in flight per lane-group.
__global__ void __launch_bounds__(256, 8) gather_kernel(const _Float16* __restrict__ H,
                                                        _Float16* __restrict__ aggH,
                                                        const int* __restrict__ rowptr,
                                                        const int* __restrict__ ssrc, int N) {
    const int tid = threadIdx.x, wave = tid >> 6, lane = tid & 63;
    const int g = lane >> 3, s = lane & 7;
    const int stride = gridDim.x * 4;
    const half8* __restrict__ Hv = (const half8*)H;
    for (int n = blockIdx.x * 4 + wave; n < N; n += stride) {
        int beg = rowptr[n], end = rowptr[n + 1];
        float a0[8], a1[8];
#pragma unroll
        for (int j = 0; j < 8; ++j) { a0[j] = 0.f; a1[j] = 0.f; }
        if (g == 0) {  // self term lives ONLY here
            half8 v = Hv[(size_t)n * 8 + s];
#pragma unroll
            for (int j = 0; j < 8; ++j) a0[j] = (1.0f + EPS) * (float)v[j];
        }
        int e = beg + g;
        for (; e + 24 < end; e += 32) {   // 4 rows in flight per group
            int i0 = ssrc[e], i1 = ssrc[e + 8], i2 = ssrc[e + 16], i3 = ssrc[e + 24];
            half8 v0 = Hv[(size_t)i0 * 8 + s];
            half8 v1 = Hv[(size_t)i1 * 8 + s];
            half8 v2 = Hv[(size_t)i2 * 8 + s];
            half8 v3 = Hv[(size_t)i3 * 8 + s];
#pragma unroll
            for (int j = 0; j < 8; ++j) {
                a0[j] += (float)v0[j] + (float)v1[j];
                a1[j] += (float)v2[j] + (float)v3[j];
            }
        }
        for (; e + 8 < end; e += 16) {    // 2 rows in flight
            int i0 = ssrc[e], i1 = ssrc[e + 8];
            half8 v0 = Hv[(size_t)i0 * 8 + s];
            half8 v1 = Hv[(size_t)i1 * 8 + s];
#pragma unroll
            for (int j = 0; j < 8; ++j) { a0[j] += (float)v0[j]; a1[j] += (float)v1[j]; }
        }
        if (e < end) {
            int i0 = ssrc[e];
            half8 v0 = Hv[(size_t)i0 * 8 + s];
#pragma unroll
            for (int j = 0; j < 8; ++j) a0[j] += (float)v0[j];
        }
        half8 o;
#pragma unroll
        for (int j = 0; j < 8; ++j) {
            float f = a0[j] + a1[j];
            f += __shfl_xor(f, 8);
            f += __shfl_xor(f, 16);
            f += __shfl_xor(f, 32);
            o[j] = (_Float16)f;
        }
        if (g == 0)
            ((half8*)aggH)[(size_t)n * 8 + s] = o;
    }
}

// ======================= MFMA MLP =======================
__global__ void __launch_bounds__(256) mlp_mfma_kernel(
    const _Float16* __restrict__ aggH, _Float16* __restrict__ Hout,
    const _Float16* __restrict__ wf1, const _Float16* __restrict__ wf2,
    const float* __restrict__ b1, const float* __restrict__ b2, int nTiles) {
    __shared__ __align__(16) _Float16 sT[4][16 * LDS_PAD];
    const int tid = threadIdx.x, wave = tid >> 6, lane = tid & 63;
    const int lr = lane & 15;    // row (A) / col (C)
    const int lg = lane >> 4;    // lane group 0..3

    half8 B1[2][4], B2[2][4];
#pragma unroll
    for (int k0 = 0; k0 < 2; ++k0)
#pragma unroll
        for (int c = 0; c < 4; ++c) {
            B1[k0][c] = *(const half8*)(wf1 + ((k0 * 4 + c) * 64 + lane) * 8);
            B2[k0][c] = *(const half8*)(wf2 + ((k0 * 4 + c) * 64 + lane) * 8);
        }
    float b1c[4], b2c[4];
#pragma unroll
    for (int c = 0; c < 4; ++c) { b1c[c] = b1[16 * c + lr]; b2c[c] = b2[16 * c + lr]; }

    _Float16* myT = sT[wave];
    const int stride = gridDim.x * 4;
    for (int tile = blockIdx.x * 4 + wave; tile < nTiles; tile += stride) {
        const size_t row0 = (size_t)tile * 16;
        half8 A0 = *(const half8*)(aggH + (row0 + lr) * DIM + lg * 8);
        half8 A1 = *(const half8*)(aggH + (row0 + lr) * DIM + 32 + lg * 8);
        f32x4 acc[4];
#pragma unroll
        for (int c = 0; c < 4; ++c) {
            acc[c] = (f32x4){0.f, 0.f, 0.f, 0.f};
            acc[c] = __builtin_amdgcn_mfma_f32_16x16x32_f16(A0, B1[0][c], acc[c], 0, 0, 0);
            acc[c] = __builtin_amdgcn_mfma_f32_16x16x32_f16(A1, B1[1][c], acc[c], 0, 0, 0);
        }
#pragma unroll
        for (int c = 0; c < 4; ++c)
#pragma unroll
            for (int j = 0; j < 4; ++j)
                myT[(lg * 4 + j) * LDS_PAD + 16 * c + lr] =
                    (_Float16)lrelu(acc[c][j] + b1c[c]);
        half8 H0 = *(const half8*)(myT + lr * LDS_PAD + lg * 8);
        half8 H1 = *(const half8*)(myT + lr * LDS_PAD + 32 + lg * 8);
#pragma unroll
        for (int c = 0; c < 4; ++c) {
            acc[c] = (f32x4){0.f, 0.f, 0.f, 0.f};
            acc[c] = __builtin_amdgcn_mfma_f32_16x16x32_f16(H0, B2[0][c], acc[c], 0, 0, 0);
            acc[c] = __builtin_amdgcn_mfma_f32_16x16x32_f16(H1, B2[1][c], acc[c], 0, 0, 0);
        }
#pragma unroll
        for (int c = 0; c < 4; ++c)
#pragma unroll
            for (int j = 0; j < 4; ++j)
                myT[(lg * 4 + j) * LDS_PAD + 16 * c + lr] =
                    (_Float16)lrelu(lrelu(acc[c][j] + b2c[c]));
#pragma unroll
        for (int q = 0; q < 2; ++q) {
            half8 o = *(const half8*)(myT + lr * LDS_PAD + (lg + 4 * q) * 8);
            *(half8*)(Hout + (row0 + lr) * DIM + (lg + 4 * q) * 8) = o;
        }
    }
}

// ======================= readout + classifier =======================
__global__ void __launch_bounds__(512) readout_f16_kernel(const _Float16* __restrict__ H,
                                                          const int* __restrict__ gid,
                                                          float* __restrict__ em, int N) {
    __shared__ float sAcc[N_GRAPHS * DIM];
    int tid = threadIdx.x;
    for (int i = tid; i < N_GRAPHS * DIM; i += 512) sAcc[i] = 0.f;
    __syncthreads();
    int lane = tid & 63, wave = tid >> 6;
    int chunk = (N + gridDim.x - 1) / gridDim.x;
    int beg = blockIdx.x * chunk;
    int end = beg + chunk; if (end > N) end = N;
    int n0 = beg + wave * 4;
    for (; n0 + 3 < end; n0 += 32) {   // 8 waves * 4 nodes
        int g0 = gid[n0], g1 = gid[n0 + 1], g2 = gid[n0 + 2], g3 = gid[n0 + 3];
        float v0 = (float)H[(size_t)(n0    ) * DIM + lane];
        float v1 = (float)H[(size_t)(n0 + 1) * DIM + lane];
        float v2 = (float)H[(size_t)(n0 + 2) * DIM + lane];
        float v3 = (float)H[(size_t)(n0 + 3) * DIM + lane];
        atomicAdd(&sAcc[g0 * DIM + lane], v0);
        atomicAdd(&sAcc[g1 * DIM + lane], v1);
        atomicAdd(&sAcc[g2 * DIM + lane], v2);
        atomicAdd(&sAcc[g3 * DIM + lane], v3);
    }
    for (int k = n0; k < end && k < n0 + 4; ++k) {
        int g = gid[k];
        atomicAdd(&sAcc[g * DIM + lane], (float)H[(size_t)k * DIM + lane]);
    }
    __syncthreads();
    for (int i = tid; i < N_GRAPHS * DIM; i += 512) atomicAdd(&em[i], sAcc[i]);
}

__global__ void __launch_bounds__(256) cls_kernel(const float* __restrict__ em,
                                                  const float* __restrict__ W1,
                                                  const float* __restrict__ b1,
                                                  const float* __restrict__ W2,
                                                  const float* __restrict__ b2,
                                                  float* __restrict__ out) {
    __shared__ float sT[N_GRAPHS * DIM];
    __shared__ float sW1[DIM * DIM];
    for (int i = threadIdx.x; i < DIM * DIM; i += 256) sW1[i] = W1[i];
    __syncthreads();
    for (int i = threadIdx.x; i < N_GRAPHS * DIM; i += 256) {
        int g = i >> 6, j = i & 63;
        float acc = b1[j];
#pragma unroll
        for (int k = 0; k < DIM; ++k) acc += em[g * DIM + k] * sW1[k * DIM + j];
        sT[i] = lrelu(acc);
    }
    __syncthreads();
    for (int i = threadIdx.x; i < N_GRAPHS * NCLS; i += 256) {
        int g = i / NCLS, c = i % NCLS;
        float acc = b2[c];
#pragma unroll
        for (int k = 0; k < DIM; ++k) acc += sT[g * DIM + k] * W2[k * NCLS + c];
        out[i] = acc;
    }
}

// ======================= fallback (atomic scatter, fp32) ================
__global__ void copy_kernel(const float* __restrict__ x, float* __restrict__ Y, int n4) {
    int i = blockIdx.x * blockDim.x + threadIdx.x;
    if (i < n4) ((float4*)Y)[i] = ((const float4*)x)[i];
}

__global__ void __launch_bounds__(256) scatter_kernel(const float* __restrict__ Y,
                                                      const int* __restrict__ src,
                                                      const int* __restrict__ dst,
                                                      float* __restrict__ agg, int E) {
    int t = blockIdx.x * blockDim.x + threadIdx.x;
    int e = t >> 4;
    if (e >= E) return;
    int f4 = t & 15;
    int s = src[e];
    int d = dst[e];
    float4 v = ((const float4*)(Y + (size_t)s * DIM))[f4];
    float* ap = agg + (size_t)d * DIM + f4 * 4;
    atomicAdd(ap + 0, v.x);
    atomicAdd(ap + 1, v.y);
    atomicAdd(ap + 2, v.z);
    atomicAdd(ap + 3, v.w);
}

__global__ void __launch_bounds__(256) mlp_kernel(float* __restrict__ Y,
                                                  const float* __restrict__ agg,
                                                  const float* __restrict__ W1,
                                                  const float* __restrict__ b1,
                                                  const float* __restrict__ W2,
                                                  const float* __restrict__ b2, int N) {
    __shared__ float sW1[DIM * DIM];
    __shared__ float sW2[DIM * DIM];
    __shared__ float sb1[DIM];
    __shared__ float sb2[DIM];
    int tid = threadIdx.x;
    for (int i = tid; i < DIM * DIM; i += 256) { sW1[i] = W1[i]; sW2[i] = W2[i]; }
    if (tid < DIM) { sb1[tid] = b1[tid]; sb2[tid] = b2[tid]; }
    __syncthreads();
    int wave = tid >> 6, lane = tid & 63;
    int base = blockIdx.x * 64;
    for (int r = wave; r < 64; r += 4) {
        int row = base + r;
        if (row >= N) break;
        size_t off = (size_t)row * DIM + lane;
        float h = (1.0f + EPS) * Y[off] + agg[off];
        float acc = sb1[lane];
#pragma unroll
        for (int k = 0; k < DIM; ++k) acc += __shfl(h, k) * sW1[k * DIM + lane];
        acc = lrelu(acc);
        float acc2 = sb2[lane];
#pragma unroll
        for (int k = 0; k < DIM; ++k) acc2 += __shfl(acc, k) * sW2[k * DIM + lane];
        Y[off] = lrelu(lrelu(acc2));
    }
}

__global__ void __launch_bounds__(256) readout_kernel(const float* __restrict__ Y,
                                                      const int* __restrict__ gid,
                                                      float* __restrict__ em, int N) {
    __shared__ float sAcc[N_GRAPHS * DIM];
    for (int i = threadIdx.x; i < N_GRAPHS * DIM; i += 256) sAcc[i] = 0.f;
    __syncthreads();
    int lane = threadIdx.x & 63, wave = threadIdx.x >> 6;
    int stride = gridDim.x * 4;
    for (int n = blockIdx.x * 4 + wave; n < N; n += stride) {
        int g = gid[n];
        atomicAdd(&sAcc[g * DIM + lane], Y[(size_t)n * DIM + lane]);
    }
    __syncthreads();
    for (int i = threadIdx.x; i < N_GRAPHS * DIM; i += 256) atomicAdd(&em[i], sAcc[i]);
}

extern "C" void kernel_launch(void* const* d_in, const int* in_sizes, int n_in,
                              void* d_out, int out_size, void* d_ws, size_t ws_size,
                              hipStream_t stream) {
    const float* x       = (const float*)d_in[0];
    const int*   src     = (const int*)d_in[1];
    const int*   dst     = (const int*)d_in[2];
    const int*   gid     = (const int*)d_in[3];
    const float* mlp0_W1 = (const float*)d_in[4];
    const float* mlp0_b1 = (const float*)d_in[5];
    const float* mlp0_W2 = (const float*)d_in[6];
    const float* mlp0_b2 = (const float*)d_in[7];
    const float* mlps_W1 = (const float*)d_in[8];
    const float* mlps_b1 = (const float*)d_in[9];
    const float* mlps_W2 = (const float*)d_in[10];
    const float* mlps_b2 = (const float*)d_in[11];
    const float* cls_W1  = (const float*)d_in[12];
    const float* cls_b1  = (const float*)d_in[13];
    const float* cls_W2  = (const float*)d_in[14];
    const float* cls_b2  = (const float*)d_in[15];
    float* out = (float*)d_out;

    const size_t szH  = (size_t)N_NODES * DIM * sizeof(_Float16);  // 12.8 MB
    const size_t szY  = (size_t)N_NODES * DIM * sizeof(float);     // 25.6 MB
    const size_t szEm = (size_t)N_GRAPHS * DIM * sizeof(float);
    const size_t szRp = (size_t)(N_NODES + 16) * sizeof(int);
    const size_t szE  = (size_t)N_EDGES * sizeof(int);             // 12.8 MB
    const size_t szT  = 512 * sizeof(int);
    const size_t szWf = 6 * 4096 * sizeof(_Float16);               // 48 KB
    const size_t need = 4 * szH + szE + szEm + szRp + 3 * szT + szWf;  // ~64.7 MB

    const float* roundB1[3] = {mlp0_b1, mlps_b1, mlps_b1 + DIM};
    const float* roundB2[3] = {mlp0_b2, mlps_b2, mlps_b2 + DIM};

    if (ws_size >= need) {
        char* w = (char*)d_ws;
        char* slabU   = w;                w += szH;   // ssrcEnc / Hx
        _Float16* Ha  = (_Float16*)w;     w += szH;
        _Float16* Hb  = (_Float16*)w;     w += szH;
        _Float16* aggH= (_Float16*)w;     w += szH;
        int*  ssrc    = (int*)w;          w += szE;
        float* em     = (float*)w;        w += szEm;
        int*  rowptr  = (int*)w;          w += szRp;
        int*  tileS   = (int*)w;          w += szT;
        int*  tileB   = (int*)w;          w += szT;
        int*  bCur    = (int*)w;          w += szT;
        _Float16* wfrag = (_Float16*)w;   w += szWf;
        int*      ssrcEnc = (int*)slabU;
        _Float16* Hx      = (_Float16*)slabU;

        // --- CSR build ---
        hipMemsetAsync(tileS, 0, szT, stream);
        int aBlocks = (N_EDGES + BIN_CH - 1) / BIN_CH;   // 391
        bcount_kernel<<<aBlocks, 256, 0, stream>>>(dst, tileS, N_EDGES);
        tile_scan_kernel<<<1, 512, 0, stream>>>(tileS, tileB, bCur, rowptr, NBKT);
        binA_kernel<<<aBlocks, 256, 0, stream>>>(src, dst, bCur, ssrcEnc, N_EDGES);
        binB_kernel<<<NBKT, 512, 0, stream>>>(ssrcEnc, tileB, rowptr, ssrc, N_EDGES, NBKT);

        // --- weights -> fp16 fragment layout ---
        wcvt_kernel<<<96, 256, 0, stream>>>(mlp0_W1, mlp0_W2, mlps_W1, mlps_W2, wfrag);

        // --- x -> fp16 (reuses ssrcEnc slab; ordered after binB) ---
        int n4 = N_NODES * DIM / 4;
        cvt_kernel<<<(n4 + 255) / 256, 256, 0, stream>>>(x, Hx, n4);

        // --- rounds: Hx -> Ha -> Hb -> Ha, gather + MFMA MLP ---
        const _Float16* Hin[3]  = {Hx, Ha, Hb};
        _Float16*       Hout[3] = {Ha, Hb, Ha};
        const int nTiles = N_NODES / 16;                  // 6250
        const int mBlocks = (nTiles + 3) / 4;             // 1563
        for (int j = 0; j < 3; ++j) {
            gather_kernel<<<2048, 256, 0, stream>>>(Hin[j], aggH, rowptr, ssrc, N_NODES);
            mlp_mfma_kernel<<<mBlocks, 256, 0, stream>>>(aggH, Hout[j],
                                                         wfrag + (size_t)(2 * j) * 4096,
                                                         wfrag + (size_t)(2 * j + 1) * 4096,
                                                         roundB1[j], roundB2[j], nTiles);
        }

        hipMemsetAsync(em, 0, szEm, stream);
        readout_f16_kernel<<<RO_BLOCKS, 512, 0, stream>>>(Ha, gid, em, N_NODES);
        cls_kernel<<<1, 256, 0, stream>>>(em, cls_W1, cls_b1, cls_W2, cls_b2, out);
    } else {
        // fallback: atomic-scatter fp32 path (needs 2*szY + szEm)
        const float* roundW1[3] = {mlp0_W1, mlps_W1, mlps_W1 + DIM * DIM};
        const float* roundW2[3] = {mlp0_W2, mlps_W2, mlps_W2 + DIM * DIM};
        float* Y   = (float*)d_ws;
        float* agg = Y + (size_t)N_NODES * DIM;
        float* em  = agg + (size_t)N_NODES * DIM;
        int n4 = N_NODES * DIM / 4;
        copy_kernel<<<(n4 + 255) / 256, 256, 0, stream>>>(x, Y, n4);
        for (int j = 0; j < 3; ++j) {
            hipMemsetAsync(agg, 0, szY, stream);
            long long threads = (long long)N_EDGES * 16;
            int blocks = (int)((threads + 255) / 256);
            scatter_kernel<<<blocks, 256, 0, stream>>>(Y, src, dst, agg, N_EDGES);
            int mb = (N_NODES + 63) / 64;
            mlp_kernel<<<mb, 256, 0, stream>>>(Y, agg, roundW1[j], roundB1[j],
                                               roundW2[j], roundB2[j], N_NODES);
        }
        hipMemsetAsync(em, 0, szEm, stream);
        readout_kernel<<<128, 256, 0, stream>>>(Y, gid, em, N_NODES);
        cls_kernel<<<1, 256, 0, stream>>>(em, cls_W1, cls_b1, cls_W2, cls_b2, out);
    }
}

// Round 12
// 359.949 us; speedup vs baseline: 1.0292x; 1.0292x over previous
//
#include <hip/hip_runtime.h>
#include <hip/hip_bf16.h>

#define N_NODES 100000
#define N_EDGES 3200000
#define N_GRAPHS 100
#define DIM 64
#define NCLS 10
#define EPS 0.1f
#define SLOPE 0.01f
#define BUCKET 256
#define BUCKET_SH 8
#define NBKT ((N_NODES + BUCKET - 1) / BUCKET)   // 391 buckets of 256 nodes
#define BIN_CH 4096                               // edges per binning block
#define LDS_PAD 72                                // halves per staged row
#define RO_BLOCKS 256                             // readout blocks

using half8  = __attribute__((ext_vector_type(8))) _Float16;
using half4v = __attribute__((ext_vector_type(4))) _Float16;
using f32x4  = __attribute__((ext_vector_type(4))) float;

__device__ __forceinline__ float lrelu(float v) {
    return v >= 0.f ? v : SLOPE * v;
}

// ======================= CSR build =======================
// per-bucket edge counts: block-local LDS histogram, 1 atomic/bucket/block
__global__ void __launch_bounds__(256) bcount_kernel(const int* __restrict__ dst,
                                                     int* __restrict__ bsize, int E) {
    __shared__ int cnt[NBKT];
    int t = threadIdx.x;
    for (int i = t; i < NBKT; i += 256) cnt[i] = 0;
    __syncthreads();
    int e0 = blockIdx.x * BIN_CH;
    int e1 = e0 + BIN_CH; if (e1 > E) e1 = E;
    for (int e = e0 + t; e < e1; e += 256)
        atomicAdd(&cnt[(unsigned)dst[e] >> BUCKET_SH], 1);
    __syncthreads();
    for (int i = t; i < NBKT; i += 256)
        if (cnt[i]) atomicAdd(&bsize[i], cnt[i]);
}

__global__ void __launch_bounds__(512) tile_scan_kernel(const int* __restrict__ tileSum,
                                                        int* __restrict__ tileBase,
                                                        int* __restrict__ bucketCur,
                                                        int* __restrict__ rowptr, int T) {
    __shared__ int sb[512];
    int t = threadIdx.x;
    int v = (t < T) ? tileSum[t] : 0;
    sb[t] = v;
    __syncthreads();
    for (int off = 1; off < 512; off <<= 1) {
        int u = (t >= off) ? sb[t - off] : 0;
        __syncthreads();
        sb[t] += u;
        __syncthreads();
    }
    if (t < T) {
        int base = sb[t] - v;
        tileBase[t]  = base;
        bucketCur[t] = base;
    }
    if (t == 511) rowptr[N_NODES] = sb[511];  // = E
}

// phase A: LDS-staged block-local bucket sort (512 threads, 4096-edge chunk),
// one global atomic per (block,bucket), per-wave dense burst copy-out.
__global__ void __launch_bounds__(512) binA_kernel(const int* __restrict__ src,
                                                   const int* __restrict__ dst,
                                                   int* __restrict__ bucketCur,
                                                   int* __restrict__ ssrcEnc, int E) {
    __shared__ int ebuf[BIN_CH];          // 16 KB staged, bucket-sorted
    __shared__ int cnt[NBKT];
    __shared__ int lbase[NBKT];
    __shared__ int wbase[NBKT];
    __shared__ int lcur[NBKT];
    __shared__ int sscan[512];
    const int t = threadIdx.x, wave = t >> 6, lane = t & 63;
    for (int i = t; i < NBKT; i += 512) cnt[i] = 0;
    __syncthreads();
    int e0 = blockIdx.x * BIN_CH;
    int e1 = e0 + BIN_CH; if (e1 > E) e1 = E;
    for (int e = e0 + t; e < e1; e += 512)
        atomicAdd(&cnt[(unsigned)dst[e] >> BUCKET_SH], 1);
    __syncthreads();
    // local exclusive scan of cnt (NBKT <= 512)
    int v = (t < NBKT) ? cnt[t] : 0;
    sscan[t] = v;
    __syncthreads();
    for (int off = 1; off < 512; off <<= 1) {
        int u = (t >= off) ? sscan[t - off] : 0;
        __syncthreads();
        sscan[t] += u;
        __syncthreads();
    }
    if (t < NBKT) {
        int lb = sscan[t] - v;
        lbase[t] = lb;
        lcur[t]  = lb;
        wbase[t] = v ? atomicAdd(&bucketCur[t], v) : 0;
    }
    __syncthreads();
    // scatter into LDS, bucket-sorted
    for (int e = e0 + t; e < e1; e += 512) {
        int d = dst[e];
        int b = (unsigned)d >> BUCKET_SH;
        int p = atomicAdd(&lcur[b], 1);
        ebuf[p] = (src[e] << BUCKET_SH) | (d & (BUCKET - 1));
    }
    __syncthreads();
    // dense copy-out: wave per bucket, lanes sweep the run
    for (int b = wave; b < NBKT; b += 8) {
        int c = cnt[b], lb = lbase[b], wb = wbase[b];
        for (int k = lane; k < c; k += 64)
            ssrcEnc[wb + k] = ebuf[lb + k];
    }
}

// phase B: per bucket (256 nodes) — count, scan -> rowptr, scatter ssrc.
// write window == read slice, L2-resident for the block's lifetime.
__global__ void __launch_bounds__(256) binB_kernel(const int* __restrict__ ssrcEnc,
                                                   const int* __restrict__ tileBase,
                                                   int* __restrict__ rowptr,
                                                   int* __restrict__ ssrc, int E, int NB) {
    __shared__ int cnt[BUCKET];
    __shared__ int sb[BUCKET];
    __shared__ int cur[BUCKET];
    int b = blockIdx.x, t = threadIdx.x;
    cnt[t] = 0;
    __syncthreads();
    int base = tileBase[b];
    int endI = (b + 1 < NB) ? tileBase[b + 1] : E;
    for (int i = base + t; i < endI; i += 256)
        atomicAdd(&cnt[ssrcEnc[i] & (BUCKET - 1)], 1);
    __syncthreads();
    int v = cnt[t];
    sb[t] = v;
    __syncthreads();
    for (int off = 1; off < 256; off <<= 1) {
        int u = (t >= off) ? sb[t - off] : 0;
        __syncthreads();
        sb[t] += u;
        __syncthreads();
    }
    int node0 = b * BUCKET;
    int nn = N_NODES - node0; if (nn > BUCKET) nn = BUCKET;
    if (t < nn) {
        int p = base + sb[t] - v;   // exclusive
        rowptr[node0 + t] = p;
        cur[t] = p;
    }
    __syncthreads();
    for (int i = base + t; i < endI; i += 256) {
        int enc = ssrcEnc[i];
        int p = atomicAdd(&cur[enc & (BUCKET - 1)], 1);
        ssrc[p] = enc >> BUCKET_SH;
    }
}

// ======================= fp32 -> fp16 conversion =======================
__global__ void __launch_bounds__(256) cvt_kernel(const float* __restrict__ x,
                                                  _Float16* __restrict__ H, int n4) {
    int i = blockIdx.x * 256 + threadIdx.x;
    if (i < n4) {
        float4 v = ((const float4*)x)[i];
        half4v h;
        h[0] = (_Float16)v.x; h[1] = (_Float16)v.y;
        h[2] = (_Float16)v.z; h[3] = (_Float16)v.w;
        ((half4v*)H)[i] = h;
    }
}

// weights -> fp16 B-fragment layout for mfma_f32_16x16x32_f16
__global__ void __launch_bounds__(256) wcvt_kernel(const float* __restrict__ W0a,
                                                   const float* __restrict__ W0b,
                                                   const float* __restrict__ Ws1,
                                                   const float* __restrict__ Ws2,
                                                   _Float16* __restrict__ wfrag) {
    int f = blockIdx.x * 256 + threadIdx.x;
    if (f >= 6 * 4096) return;
    int i = f & 7, lane = (f >> 3) & 63, c = (f >> 9) & 3, k0 = (f >> 11) & 1, mat = f >> 12;
    int k = 32 * k0 + (lane >> 4) * 8 + i;
    int n = 16 * c + (lane & 15);
    const float* Wsrc;
    switch (mat) {
        case 0: Wsrc = W0a;        break;
        case 1: Wsrc = W0b;        break;
        case 2: Wsrc = Ws1;        break;
        case 3: Wsrc = Ws2;        break;
        case 4: Wsrc = Ws1 + 4096; break;
        default: Wsrc = Ws2 + 4096; break;
    }
    wfrag[f] = (_Float16)Wsrc[k * DIM + n];
}

// ======================= pure gather (max occupancy, no LDS) ============
// aggH OWNS the self term. 8 lanes/edge; 4 rows in flight per lane-group.
__global__ void __launch_bounds__(256, 8) gather_kernel(const _Float16* __restrict__ H,
                                                        _Float16* __restrict__ aggH,
                                                        const int* __restrict__ rowptr,
                                                        const int* __restrict__ ssrc, int N) {
    const int tid = threadIdx.x, wave = tid >> 6, lane = tid & 63;
    const int g = lane >> 3, s = lane & 7;
    const int stride = gridDim.x * 4;
    const half8* __restrict__ Hv = (const half8*)H;
    for (int n = blockIdx.x * 4 + wave; n < N; n += stride) {
        int beg = rowptr[n], end = rowptr[n + 1];
        float a0[8], a1[8];
#pragma unroll
        for (int j = 0; j < 8; ++j) { a0[j] = 0.f; a1[j] = 0.f; }
        if (g == 0) {  // self term lives ONLY here
            half8 v = Hv[(size_t)n * 8 + s];
#pragma unroll
            for (int j = 0; j < 8; ++j) a0[j] = (1.0f + EPS) * (float)v[j];
        }
        int e = beg + g;
        for (; e + 24 < end; e += 32) {   // 4 rows in flight per group
            int i0 = ssrc[e], i1 = ssrc[e + 8], i2 = ssrc[e + 16], i3 = ssrc[e + 24];
            half8 v0 = Hv[(size_t)i0 * 8 + s];
            half8 v1 = Hv[(size_t)i1 * 8 + s];
            half8 v2 = Hv[(size_t)i2 * 8 + s];
            half8 v3 = Hv[(size_t)i3 * 8 + s];
#pragma unroll
            for (int j = 0; j < 8; ++j) {
                a0[j] += (float)v0[j] + (float)v1[j];
                a1[j] += (float)v2[j] + (float)v3[j];
            }
        }
        for (; e + 8 < end; e += 16) {    // 2 rows in flight
            int i0 = ssrc[e], i1 = ssrc[e + 8];
            half8 v0 = Hv[(size_t)i0 * 8 + s];
            half8 v1 = Hv[(size_t)i1 * 8 + s];
#pragma unroll
            for (int j = 0; j < 8; ++j) { a0[j] += (float)v0[j]; a1[j] += (float)v1[j]; }
        }
        if (e < end) {
            int i0 = ssrc[e];
            half8 v0 = Hv[(size_t)i0 * 8 + s];
#pragma unroll
            for (int j = 0; j < 8; ++j) a0[j] += (float)v0[j];
        }
        half8 o;
#pragma unroll
        for (int j = 0; j < 8; ++j) {
            float f = a0[j] + a1[j];
            f += __shfl_xor(f, 8);
            f += __shfl_xor(f, 16);
            f += __shfl_xor(f, 32);
            o[j] = (_Float16)f;
        }
        if (g == 0)
            ((half8*)aggH)[(size_t)n * 8 + s] = o;
    }
}

// ======================= MFMA MLP =======================
__global__ void __launch_bounds__(256) mlp_mfma_kernel(
    const _Float16* __restrict__ aggH, _Float16* __restrict__ Hout,
    const _Float16* __restrict__ wf1, const _Float16* __restrict__ wf2,
    const float* __restrict__ b1, const float* __restrict__ b2, int nTiles) {
    __shared__ __align__(16) _Float16 sT[4][16 * LDS_PAD];
    const int tid = threadIdx.x, wave = tid >> 6, lane = tid & 63;
    const int lr = lane & 15;    // row (A) / col (C)
    const int lg = lane >> 4;    // lane group 0..3

    half8 B1[2][4], B2[2][4];
#pragma unroll
    for (int k0 = 0; k0 < 2; ++k0)
#pragma unroll
        for (int c = 0; c < 4; ++c) {
            B1[k0][c] = *(const half8*)(wf1 + ((k0 * 4 + c) * 64 + lane) * 8);
            B2[k0][c] = *(const half8*)(wf2 + ((k0 * 4 + c) * 64 + lane) * 8);
        }
    float b1c[4], b2c[4];
#pragma unroll
    for (int c = 0; c < 4; ++c) { b1c[c] = b1[16 * c + lr]; b2c[c] = b2[16 * c + lr]; }

    _Float16* myT = sT[wave];
    const int stride = gridDim.x * 4;
    for (int tile = blockIdx.x * 4 + wave; tile < nTiles; tile += stride) {
        const size_t row0 = (size_t)tile * 16;
        half8 A0 = *(const half8*)(aggH + (row0 + lr) * DIM + lg * 8);
        half8 A1 = *(const half8*)(aggH + (row0 + lr) * DIM + 32 + lg * 8);
        f32x4 acc[4];
#pragma unroll
        for (int c = 0; c < 4; ++c) {
            acc[c] = (f32x4){0.f, 0.f, 0.f, 0.f};
            acc[c] = __builtin_amdgcn_mfma_f32_16x16x32_f16(A0, B1[0][c], acc[c], 0, 0, 0);
            acc[c] = __builtin_amdgcn_mfma_f32_16x16x32_f16(A1, B1[1][c], acc[c], 0, 0, 0);
        }
#pragma unroll
        for (int c = 0; c < 4; ++c)
#pragma unroll
            for (int j = 0; j < 4; ++j)
                myT[(lg * 4 + j) * LDS_PAD + 16 * c + lr] =
                    (_Float16)lrelu(acc[c][j] + b1c[c]);
        half8 H0 = *(const half8*)(myT + lr * LDS_PAD + lg * 8);
        half8 H1 = *(const half8*)(myT + lr * LDS_PAD + 32 + lg * 8);
#pragma unroll
        for (int c = 0; c < 4; ++c) {
            acc[c] = (f32x4){0.f, 0.f, 0.f, 0.f};
            acc[c] = __builtin_amdgcn_mfma_f32_16x16x32_f16(H0, B2[0][c], acc[c], 0, 0, 0);
            acc[c] = __builtin_amdgcn_mfma_f32_16x16x32_f16(H1, B2[1][c], acc[c], 0, 0, 0);
        }
#pragma unroll
        for (int c = 0; c < 4; ++c)
#pragma unroll
            for (int j = 0; j < 4; ++j)
                myT[(lg * 4 + j) * LDS_PAD + 16 * c + lr] =
                    (_Float16)lrelu(lrelu(acc[c][j] + b2c[c]));
#pragma unroll
        for (int q = 0; q < 2; ++q) {
            half8 o = *(const half8*)(myT + lr * LDS_PAD + (lg + 4 * q) * 8);
            *(half8*)(Hout + (row0 + lr) * DIM + (lg + 4 * q) * 8) = o;
        }
    }
}

// ======================= readout + classifier =======================
__global__ void __launch_bounds__(512) readout_f16_kernel(const _Float16* __restrict__ H,
                                                          const int* __restrict__ gid,
                                                          float* __restrict__ em, int N) {
    __shared__ float sAcc[N_GRAPHS * DIM];
    int tid = threadIdx.x;
    for (int i = tid; i < N_GRAPHS * DIM; i += 512) sAcc[i] = 0.f;
    __syncthreads();
    int lane = tid & 63, wave = tid >> 6;
    int chunk = (N + gridDim.x - 1) / gridDim.x;
    int beg = blockIdx.x * chunk;
    int end = beg + chunk; if (end > N) end = N;
    int n0 = beg + wave * 4;
    for (; n0 + 3 < end; n0 += 32) {   // 8 waves * 4 nodes
        int g0 = gid[n0], g1 = gid[n0 + 1], g2 = gid[n0 + 2], g3 = gid[n0 + 3];
        float v0 = (float)H[(size_t)(n0    ) * DIM + lane];
        float v1 = (float)H[(size_t)(n0 + 1) * DIM + lane];
        float v2 = (float)H[(size_t)(n0 + 2) * DIM + lane];
        float v3 = (float)H[(size_t)(n0 + 3) * DIM + lane];
        atomicAdd(&sAcc[g0 * DIM + lane], v0);
        atomicAdd(&sAcc[g1 * DIM + lane], v1);
        atomicAdd(&sAcc[g2 * DIM + lane], v2);
        atomicAdd(&sAcc[g3 * DIM + lane], v3);
    }
    for (int k = n0; k < end && k < n0 + 4; ++k) {
        int g = gid[k];
        atomicAdd(&sAcc[g * DIM + lane], (float)H[(size_t)k * DIM + lane]);
    }
    __syncthreads();
    for (int i = tid; i < N_GRAPHS * DIM; i += 512) atomicAdd(&em[i], sAcc[i]);
}

__global__ void __launch_bounds__(256) cls_kernel(const float* __restrict__ em,
                                                  const float* __restrict__ W1,
                                                  const float* __restrict__ b1,
                                                  const float* __restrict__ W2,
                                                  const float* __restrict__ b2,
                                                  float* __restrict__ out) {
    __shared__ float sT[N_GRAPHS * DIM];
    __shared__ float sW1[DIM * DIM];
    for (int i = threadIdx.x; i < DIM * DIM; i += 256) sW1[i] = W1[i];
    __syncthreads();
    for (int i = threadIdx.x; i < N_GRAPHS * DIM; i += 256) {
        int g = i >> 6, j = i & 63;
        float acc = b1[j];
#pragma unroll
        for (int k = 0; k < DIM; ++k) acc += em[g * DIM + k] * sW1[k * DIM + j];
        sT[i] = lrelu(acc);
    }
    __syncthreads();
    for (int i = threadIdx.x; i < N_GRAPHS * NCLS; i += 256) {
        int g = i / NCLS, c = i % NCLS;
        float acc = b2[c];
#pragma unroll
        for (int k = 0; k < DIM; ++k) acc += sT[g * DIM + k] * W2[k * NCLS + c];
        out[i] = acc;
    }
}

// ======================= fallback (atomic scatter, fp32) ================
__global__ void copy_kernel(const float* __restrict__ x, float* __restrict__ Y, int n4) {
    int i = blockIdx.x * blockDim.x + threadIdx.x;
    if (i < n4) ((float4*)Y)[i] = ((const float4*)x)[i];
}

__global__ void __launch_bounds__(256) scatter_kernel(const float* __restrict__ Y,
                                                      const int* __restrict__ src,
                                                      const int* __restrict__ dst,
                                                      float* __restrict__ agg, int E) {
    int t = blockIdx.x * blockDim.x + threadIdx.x;
    int e = t >> 4;
    if (e >= E) return;
    int f4 = t & 15;
    int s = src[e];
    int d = dst[e];
    float4 v = ((const float4*)(Y + (size_t)s * DIM))[f4];
    float* ap = agg + (size_t)d * DIM + f4 * 4;
    atomicAdd(ap + 0, v.x);
    atomicAdd(ap + 1, v.y);
    atomicAdd(ap + 2, v.z);
    atomicAdd(ap + 3, v.w);
}

__global__ void __launch_bounds__(256) mlp_kernel(float* __restrict__ Y,
                                                  const float* __restrict__ agg,
                                                  const float* __restrict__ W1,
                                                  const float* __restrict__ b1,
                                                  const float* __restrict__ W2,
                                                  const float* __restrict__ b2, int N) {
    __shared__ float sW1[DIM * DIM];
    __shared__ float sW2[DIM * DIM];
    __shared__ float sb1[DIM];
    __shared__ float sb2[DIM];
    int tid = threadIdx.x;
    for (int i = tid; i < DIM * DIM; i += 256) { sW1[i] = W1[i]; sW2[i] = W2[i]; }
    if (tid < DIM) { sb1[tid] = b1[tid]; sb2[tid] = b2[tid]; }
    __syncthreads();
    int wave = tid >> 6, lane = tid & 63;
    int base = blockIdx.x * 64;
    for (int r = wave; r < 64; r += 4) {
        int row = base + r;
        if (row >= N) break;
        size_t off = (size_t)row * DIM + lane;
        float h = (1.0f + EPS) * Y[off] + agg[off];
        float acc = sb1[lane];
#pragma unroll
        for (int k = 0; k < DIM; ++k) acc += __shfl(h, k) * sW1[k * DIM + lane];
        acc = lrelu(acc);
        float acc2 = sb2[lane];
#pragma unroll
        for (int k = 0; k < DIM; ++k) acc2 += __shfl(acc, k) * sW2[k * DIM + lane];
        Y[off] = lrelu(lrelu(acc2));
    }
}

__global__ void __launch_bounds__(256) readout_kernel(const float* __restrict__ Y,
                                                      const int* __restrict__ gid,
                                                      float* __restrict__ em, int N) {
    __shared__ float sAcc[N_GRAPHS * DIM];
    for (int i = threadIdx.x; i < N_GRAPHS * DIM; i += 256) sAcc[i] = 0.f;
    __syncthreads();
    int lane = threadIdx.x & 63, wave = threadIdx.x >> 6;
    int stride = gridDim.x * 4;
    for (int n = blockIdx.x * 4 + wave; n < N; n += stride) {
        int g = gid[n];
        atomicAdd(&sAcc[g * DIM + lane], Y[(size_t)n * DIM + lane]);
    }
    __syncthreads();
    for (int i = threadIdx.x; i < N_GRAPHS * DIM; i += 256) atomicAdd(&em[i], sAcc[i]);
}

extern "C" void kernel_launch(void* const* d_in, const int* in_sizes, int n_in,
                              void* d_out, int out_size, void* d_ws, size_t ws_size,
                              hipStream_t stream) {
    const float* x       = (const float*)d_in[0];
    const int*   src     = (const int*)d_in[1];
    const int*   dst     = (const int*)d_in[2];
    const int*   gid     = (const int*)d_in[3];
    const float* mlp0_W1 = (const float*)d_in[4];
    const float* mlp0_b1 = (const float*)d_in[5];
    const float* mlp0_W2 = (const float*)d_in[6];
    const float* mlp0_b2 = (const float*)d_in[7];
    const float* mlps_W1 = (const float*)d_in[8];
    const float* mlps_b1 = (const float*)d_in[9];
    const float* mlps_W2 = (const float*)d_in[10];
    const float* mlps_b2 = (const float*)d_in[11];
    const float* cls_W1  = (const float*)d_in[12];
    const float* cls_b1  = (const float*)d_in[13];
    const float* cls_W2  = (const float*)d_in[14];
    const float* cls_b2  = (const float*)d_in[15];
    float* out = (float*)d_out;

    const size_t szH  = (size_t)N_NODES * DIM * sizeof(_Float16);  // 12.8 MB
    const size_t szY  = (size_t)N_NODES * DIM * sizeof(float);     // 25.6 MB
    const size_t szEm = (size_t)N_GRAPHS * DIM * sizeof(float);
    const size_t szRp = (size_t)(N_NODES + 16) * sizeof(int);
    const size_t szE  = (size_t)N_EDGES * sizeof(int);             // 12.8 MB
    const size_t szT  = 512 * sizeof(int);
    const size_t szWf = 6 * 4096 * sizeof(_Float16);               // 48 KB
    const size_t need = 4 * szH + szE + szEm + szRp + 3 * szT + szWf;  // ~64.7 MB

    const float* roundB1[3] = {mlp0_b1, mlps_b1, mlps_b1 + DIM};
    const float* roundB2[3] = {mlp0_b2, mlps_b2, mlps_b2 + DIM};

    if (ws_size >= need) {
        char* w = (char*)d_ws;
        char* slabU   = w;                w += szH;   // ssrcEnc / Hx
        _Float16* Ha  = (_Float16*)w;     w += szH;
        _Float16* Hb  = (_Float16*)w;     w += szH;
        _Float16* aggH= (_Float16*)w;     w += szH;
        int*  ssrc    = (int*)w;          w += szE;
        float* em     = (float*)w;        w += szEm;
        int*  rowptr  = (int*)w;          w += szRp;
        int*  tileS   = (int*)w;          w += szT;
        int*  tileB   = (int*)w;          w += szT;
        int*  bCur    = (int*)w;          w += szT;
        _Float16* wfrag = (_Float16*)w;   w += szWf;
        int*      ssrcEnc = (int*)slabU;
        _Float16* Hx      = (_Float16*)slabU;

        // --- CSR build ---
        hipMemsetAsync(tileS, 0, szT, stream);
        int aBlocks = (N_EDGES + BIN_CH - 1) / BIN_CH;   // 782
        bcount_kernel<<<aBlocks, 256, 0, stream>>>(dst, tileS, N_EDGES);
        tile_scan_kernel<<<1, 512, 0, stream>>>(tileS, tileB, bCur, rowptr, NBKT);
        binA_kernel<<<aBlocks, 512, 0, stream>>>(src, dst, bCur, ssrcEnc, N_EDGES);
        binB_kernel<<<NBKT, 256, 0, stream>>>(ssrcEnc, tileB, rowptr, ssrc, N_EDGES, NBKT);

        // --- weights -> fp16 fragment layout ---
        wcvt_kernel<<<96, 256, 0, stream>>>(mlp0_W1, mlp0_W2, mlps_W1, mlps_W2, wfrag);

        // --- x -> fp16 (reuses ssrcEnc slab; ordered after binB) ---
        int n4 = N_NODES * DIM / 4;
        cvt_kernel<<<(n4 + 255) / 256, 256, 0, stream>>>(x, Hx, n4);

        // --- rounds: Hx -> Ha -> Hb -> Ha, gather + MFMA MLP ---
        const _Float16* Hin[3]  = {Hx, Ha, Hb};
        _Float16*       Hout[3] = {Ha, Hb, Ha};
        const int nTiles = N_NODES / 16;                  // 6250
        const int mBlocks = (nTiles + 3) / 4;             // 1563
        for (int j = 0; j < 3; ++j) {
            gather_kernel<<<4096, 256, 0, stream>>>(Hin[j], aggH, rowptr, ssrc, N_NODES);
            mlp_mfma_kernel<<<mBlocks, 256, 0, stream>>>(aggH, Hout[j],
                                                         wfrag + (size_t)(2 * j) * 4096,
                                                         wfrag + (size_t)(2 * j + 1) * 4096,
                                                         roundB1[j], roundB2[j], nTiles);
        }

        hipMemsetAsync(em, 0, szEm, stream);
        readout_f16_kernel<<<RO_BLOCKS, 512, 0, stream>>>(Ha, gid, em, N_NODES);
        cls_kernel<<<1, 256, 0, stream>>>(em, cls_W1, cls_b1, cls_W2, cls_b2, out);
    } else {
        // fallback: atomic-scatter fp32 path (needs 2*szY + szEm)
        const float* roundW1[3] = {mlp0_W1, mlps_W1, mlps_W1 + DIM * DIM};
        const float* roundW2[3] = {mlp0_W2, mlps_W2, mlps_W2 + DIM * DIM};
        float* Y   = (float*)d_ws;
        float* agg = Y + (size_t)N_NODES * DIM;
        float* em  = agg + (size_t)N_NODES * DIM;
        int n4 = N_NODES * DIM / 4;
        copy_kernel<<<(n4 + 255) / 256, 256, 0, stream>>>(x, Y, n4);
        for (int j = 0; j < 3; ++j) {
            hipMemsetAsync(agg, 0, szY, stream);
            long long threads = (long long)N_EDGES * 16;
            int blocks = (int)((threads + 255) / 256);
            scatter_kernel<<<blocks, 256, 0, stream>>>(Y, src, dst, agg, N_EDGES);
            int mb = (N_NODES + 63) / 64;
            mlp_kernel<<<mb, 256, 0, stream>>>(Y, agg, roundW1[j], roundB1[j],
                                               roundW2[j], roundB2[j], N_NODES);
        }
        hipMemsetAsync(em, 0, szEm, stream);
        readout_kernel<<<128, 256, 0, stream>>>(Y, gid, em, N_NODES);
        cls_kernel<<<1, 256, 0, stream>>>(em, cls_W1, cls_b1, cls_W2, cls_b2, out);
    }
}

// Round 13
// 355.371 us; speedup vs baseline: 1.0425x; 1.0129x over previous
//
#include <hip/hip_runtime.h>
#include <hip/hip_bf16.h>

#define N_NODES 100000
#define N_EDGES 3200000
#define N_GRAPHS 100
#define DIM 64
#define NCLS 10
#define EPS 0.1f
#define SLOPE 0.01f
#define BUCKET 256
#define BUCKET_SH 8
#define NBKT ((N_NODES + BUCKET - 1) / BUCKET)   // 391 buckets of 256 nodes
#define BIN_CH 4096                               // edges per binning block
#define LDS_PAD 72                                // halves per staged row
#define RO_BLOCKS 256                             // readout blocks
#define MLP_BLOCKS 392                            // 4 tiles per wave

using half8  = __attribute__((ext_vector_type(8))) _Float16;
using half4v = __attribute__((ext_vector_type(4))) _Float16;
using f32x4  = __attribute__((ext_vector_type(4))) float;

__device__ __forceinline__ float lrelu(float v) {
    return v >= 0.f ? v : SLOPE * v;
}

// ======================= CSR build =======================
// per-bucket edge counts: int4 reads, block-local LDS histogram,
// 1 atomic/bucket/block
__global__ void __launch_bounds__(256) bcount_kernel(const int* __restrict__ dst,
                                                     int* __restrict__ bsize, int E) {
    __shared__ int cnt[NBKT];
    int t = threadIdx.x;
    for (int i = t; i < NBKT; i += 256) cnt[i] = 0;
    __syncthreads();
    int e0 = blockIdx.x * BIN_CH;
    int e1 = e0 + BIN_CH; if (e1 > E) e1 = E;
    int e = e0 + t * 4;
    for (; e + 3 < e1; e += 1024) {
        int4 d4 = *(const int4*)(dst + e);
        atomicAdd(&cnt[(unsigned)d4.x >> BUCKET_SH], 1);
        atomicAdd(&cnt[(unsigned)d4.y >> BUCKET_SH], 1);
        atomicAdd(&cnt[(unsigned)d4.z >> BUCKET_SH], 1);
        atomicAdd(&cnt[(unsigned)d4.w >> BUCKET_SH], 1);
    }
    for (int k = e; k < e1 && k < e + 4; ++k)
        atomicAdd(&cnt[(unsigned)dst[k] >> BUCKET_SH], 1);
    __syncthreads();
    for (int i = t; i < NBKT; i += 256)
        if (cnt[i]) atomicAdd(&bsize[i], cnt[i]);
}

__global__ void __launch_bounds__(512) tile_scan_kernel(const int* __restrict__ tileSum,
                                                        int* __restrict__ tileBase,
                                                        int* __restrict__ bucketCur,
                                                        int* __restrict__ rowptr, int T) {
    __shared__ int sb[512];
    int t = threadIdx.x;
    int v = (t < T) ? tileSum[t] : 0;
    sb[t] = v;
    __syncthreads();
    for (int off = 1; off < 512; off <<= 1) {
        int u = (t >= off) ? sb[t - off] : 0;
        __syncthreads();
        sb[t] += u;
        __syncthreads();
    }
    if (t < T) {
        int base = sb[t] - v;
        tileBase[t]  = base;
        bucketCur[t] = base;
    }
    if (t == 511) rowptr[N_NODES] = sb[511];  // = E
}

// phase A: LDS-staged block-local bucket sort (512 threads, 4096-edge chunk),
// int4 edge reads, one global atomic per (block,bucket), per-wave dense
// burst copy-out.
__global__ void __launch_bounds__(512) binA_kernel(const int* __restrict__ src,
                                                   const int* __restrict__ dst,
                                                   int* __restrict__ bucketCur,
                                                   int* __restrict__ ssrcEnc, int E) {
    __shared__ int ebuf[BIN_CH];          // 16 KB staged, bucket-sorted
    __shared__ int cnt[NBKT];
    __shared__ int lbase[NBKT];
    __shared__ int wbase[NBKT];
    __shared__ int lcur[NBKT];
    __shared__ int sscan[512];
    const int t = threadIdx.x, wave = t >> 6, lane = t & 63;
    for (int i = t; i < NBKT; i += 512) cnt[i] = 0;
    __syncthreads();
    int e0 = blockIdx.x * BIN_CH;
    int e1 = e0 + BIN_CH; if (e1 > E) e1 = E;
    {
        int e = e0 + t * 4;
        for (; e + 3 < e1; e += 2048) {
            int4 d4 = *(const int4*)(dst + e);
            atomicAdd(&cnt[(unsigned)d4.x >> BUCKET_SH], 1);
            atomicAdd(&cnt[(unsigned)d4.y >> BUCKET_SH], 1);
            atomicAdd(&cnt[(unsigned)d4.z >> BUCKET_SH], 1);
            atomicAdd(&cnt[(unsigned)d4.w >> BUCKET_SH], 1);
        }
        for (int k = e; k < e1 && k < e + 4; ++k)
            atomicAdd(&cnt[(unsigned)dst[k] >> BUCKET_SH], 1);
    }
    __syncthreads();
    // local exclusive scan of cnt (NBKT <= 512)
    int v = (t < NBKT) ? cnt[t] : 0;
    sscan[t] = v;
    __syncthreads();
    for (int off = 1; off < 512; off <<= 1) {
        int u = (t >= off) ? sscan[t - off] : 0;
        __syncthreads();
        sscan[t] += u;
        __syncthreads();
    }
    if (t < NBKT) {
        int lb = sscan[t] - v;
        lbase[t] = lb;
        lcur[t]  = lb;
        wbase[t] = v ? atomicAdd(&bucketCur[t], v) : 0;
    }
    __syncthreads();
    // scatter into LDS, bucket-sorted (int4 reads of src+dst)
    {
        int e = e0 + t * 4;
        for (; e + 3 < e1; e += 2048) {
            int4 d4 = *(const int4*)(dst + e);
            int4 s4 = *(const int4*)(src + e);
            int p;
            p = atomicAdd(&lcur[(unsigned)d4.x >> BUCKET_SH], 1);
            ebuf[p] = (s4.x << BUCKET_SH) | (d4.x & (BUCKET - 1));
            p = atomicAdd(&lcur[(unsigned)d4.y >> BUCKET_SH], 1);
            ebuf[p] = (s4.y << BUCKET_SH) | (d4.y & (BUCKET - 1));
            p = atomicAdd(&lcur[(unsigned)d4.z >> BUCKET_SH], 1);
            ebuf[p] = (s4.z << BUCKET_SH) | (d4.z & (BUCKET - 1));
            p = atomicAdd(&lcur[(unsigned)d4.w >> BUCKET_SH], 1);
            ebuf[p] = (s4.w << BUCKET_SH) | (d4.w & (BUCKET - 1));
        }
        for (int k = e; k < e1 && k < e + 4; ++k) {
            int d = dst[k];
            int p = atomicAdd(&lcur[(unsigned)d >> BUCKET_SH], 1);
            ebuf[p] = (src[k] << BUCKET_SH) | (d & (BUCKET - 1));
        }
    }
    __syncthreads();
    // dense copy-out: wave per bucket, lanes sweep the run
    for (int b = wave; b < NBKT; b += 8) {
        int c = cnt[b], lb = lbase[b], wb = wbase[b];
        for (int k = lane; k < c; k += 64)
            ssrcEnc[wb + k] = ebuf[lb + k];
    }
}

// phase B: per bucket (256 nodes) — count, scan -> rowptr, scatter ssrc.
__global__ void __launch_bounds__(256) binB_kernel(const int* __restrict__ ssrcEnc,
                                                   const int* __restrict__ tileBase,
                                                   int* __restrict__ rowptr,
                                                   int* __restrict__ ssrc, int E, int NB) {
    __shared__ int cnt[BUCKET];
    __shared__ int sb[BUCKET];
    __shared__ int cur[BUCKET];
    int b = blockIdx.x, t = threadIdx.x;
    cnt[t] = 0;
    __syncthreads();
    int base = tileBase[b];
    int endI = (b + 1 < NB) ? tileBase[b + 1] : E;
    for (int i = base + t; i < endI; i += 256)
        atomicAdd(&cnt[ssrcEnc[i] & (BUCKET - 1)], 1);
    __syncthreads();
    int v = cnt[t];
    sb[t] = v;
    __syncthreads();
    for (int off = 1; off < 256; off <<= 1) {
        int u = (t >= off) ? sb[t - off] : 0;
        __syncthreads();
        sb[t] += u;
        __syncthreads();
    }
    int node0 = b * BUCKET;
    int nn = N_NODES - node0; if (nn > BUCKET) nn = BUCKET;
    if (t < nn) {
        int p = base + sb[t] - v;   // exclusive
        rowptr[node0 + t] = p;
        cur[t] = p;
    }
    __syncthreads();
    for (int i = base + t; i < endI; i += 256) {
        int enc = ssrcEnc[i];
        int p = atomicAdd(&cur[enc & (BUCKET - 1)], 1);
        ssrc[p] = enc >> BUCKET_SH;
    }
}

// ======================= fp32 -> fp16 conversion =======================
__global__ void __launch_bounds__(256) cvt_kernel(const float* __restrict__ x,
                                                  _Float16* __restrict__ H, int n4) {
    int i = blockIdx.x * 256 + threadIdx.x;
    if (i < n4) {
        float4 v = ((const float4*)x)[i];
        half4v h;
        h[0] = (_Float16)v.x; h[1] = (_Float16)v.y;
        h[2] = (_Float16)v.z; h[3] = (_Float16)v.w;
        ((half4v*)H)[i] = h;
    }
}

// weights -> fp16 B-fragment layout for mfma_f32_16x16x32_f16
__global__ void __launch_bounds__(256) wcvt_kernel(const float* __restrict__ W0a,
                                                   const float* __restrict__ W0b,
                                                   const float* __restrict__ Ws1,
                                                   const float* __restrict__ Ws2,
                                                   _Float16* __restrict__ wfrag) {
    int f = blockIdx.x * 256 + threadIdx.x;
    if (f >= 6 * 4096) return;
    int i = f & 7, lane = (f >> 3) & 63, c = (f >> 9) & 3, k0 = (f >> 11) & 1, mat = f >> 12;
    int k = 32 * k0 + (lane >> 4) * 8 + i;
    int n = 16 * c + (lane & 15);
    const float* Wsrc;
    switch (mat) {
        case 0: Wsrc = W0a;        break;
        case 1: Wsrc = W0b;        break;
        case 2: Wsrc = Ws1;        break;
        case 3: Wsrc = Ws2;        break;
        case 4: Wsrc = Ws1 + 4096; break;
        default: Wsrc = Ws2 + 4096; break;
    }
    wfrag[f] = (_Float16)Wsrc[k * DIM + n];
}

// ======================= pure gather (max occupancy, no LDS) ============
// aggH OWNS the self term. 8 lanes/edge; 4 rows in flight per lane-group.
__global__ void __launch_bounds__(256, 8) gather_kernel(const _Float16* __restrict__ H,
                                                        _Float16* __restrict__ aggH,
                                                        const int* __restrict__ rowptr,
                                                        const int* __restrict__ ssrc, int N) {
    const int tid = threadIdx.x, wave = tid >> 6, lane = tid & 63;
    const int g = lane >> 3, s = lane & 7;
    const int stride = gridDim.x * 4;
    const half8* __restrict__ Hv = (const half8*)H;
    for (int n = blockIdx.x * 4 + wave; n < N; n += stride) {
        int beg = rowptr[n], end = rowptr[n + 1];
        float a0[8], a1[8];
#pragma unroll
        for (int j = 0; j < 8; ++j) { a0[j] = 0.f; a1[j] = 0.f; }
        if (g == 0) {  // self term lives ONLY here
            half8 v = Hv[(size_t)n * 8 + s];
#pragma unroll
            for (int j = 0; j < 8; ++j) a0[j] = (1.0f + EPS) * (float)v[j];
        }
        int e = beg + g;
        for (; e + 24 < end; e += 32) {   // 4 rows in flight per group
            int i0 = ssrc[e], i1 = ssrc[e + 8], i2 = ssrc[e + 16], i3 = ssrc[e + 24];
            half8 v0 = Hv[(size_t)i0 * 8 + s];
            half8 v1 = Hv[(size_t)i1 * 8 + s];
            half8 v2 = Hv[(size_t)i2 * 8 + s];
            half8 v3 = Hv[(size_t)i3 * 8 + s];
#pragma unroll
            for (int j = 0; j < 8; ++j) {
                a0[j] += (float)v0[j] + (float)v1[j];
                a1[j] += (float)v2[j] + (float)v3[j];
            }
        }
        for (; e + 8 < end; e += 16) {    // 2 rows in flight
            int i0 = ssrc[e], i1 = ssrc[e + 8];
            half8 v0 = Hv[(size_t)i0 * 8 + s];
            half8 v1 = Hv[(size_t)i1 * 8 + s];
#pragma unroll
            for (int j = 0; j < 8; ++j) { a0[j] += (float)v0[j]; a1[j] += (float)v1[j]; }
        }
        if (e < end) {
            int i0 = ssrc[e];
            half8 v0 = Hv[(size_t)i0 * 8 + s];
#pragma unroll
            for (int j = 0; j < 8; ++j) a0[j] += (float)v0[j];
        }
        half8 o;
#pragma unroll
        for (int j = 0; j < 8; ++j) {
            float f = a0[j] + a1[j];
            f += __shfl_xor(f, 8);
            f += __shfl_xor(f, 16);
            f += __shfl_xor(f, 32);
            o[j] = (_Float16)f;
        }
        if (g == 0)
            ((half8*)aggH)[(size_t)n * 8 + s] = o;
    }
}

// ======================= MFMA MLP =======================
// 392 blocks -> each wave handles ~4 tiles, amortizing the B-frag preamble.
__global__ void __launch_bounds__(256) mlp_mfma_kernel(
    const _Float16* __restrict__ aggH, _Float16* __restrict__ Hout,
    const _Float16* __restrict__ wf1, const _Float16* __restrict__ wf2,
    const float* __restrict__ b1, const float* __restrict__ b2, int nTiles) {
    __shared__ __align__(16) _Float16 sT[4][16 * LDS_PAD];
    const int tid = threadIdx.x, wave = tid >> 6, lane = tid & 63;
    const int lr = lane & 15;    // row (A) / col (C)
    const int lg = lane >> 4;    // lane group 0..3

    half8 B1[2][4], B2[2][4];
#pragma unroll
    for (int k0 = 0; k0 < 2; ++k0)
#pragma unroll
        for (int c = 0; c < 4; ++c) {
            B1[k0][c] = *(const half8*)(wf1 + ((k0 * 4 + c) * 64 + lane) * 8);
            B2[k0][c] = *(const half8*)(wf2 + ((k0 * 4 + c) * 64 + lane) * 8);
        }
    float b1c[4], b2c[4];
#pragma unroll
    for (int c = 0; c < 4; ++c) { b1c[c] = b1[16 * c + lr]; b2c[c] = b2[16 * c + lr]; }

    _Float16* myT = sT[wave];
    const int stride = gridDim.x * 4;
    for (int tile = blockIdx.x * 4 + wave; tile < nTiles; tile += stride) {
        const size_t row0 = (size_t)tile * 16;
        half8 A0 = *(const half8*)(aggH + (row0 + lr) * DIM + lg * 8);
        half8 A1 = *(const half8*)(aggH + (row0 + lr) * DIM + 32 + lg * 8);
        f32x4 acc[4];
#pragma unroll
        for (int c = 0; c < 4; ++c) {
            acc[c] = (f32x4){0.f, 0.f, 0.f, 0.f};
            acc[c] = __builtin_amdgcn_mfma_f32_16x16x32_f16(A0, B1[0][c], acc[c], 0, 0, 0);
            acc[c] = __builtin_amdgcn_mfma_f32_16x16x32_f16(A1, B1[1][c], acc[c], 0, 0, 0);
        }
#pragma unroll
        for (int c = 0; c < 4; ++c)
#pragma unroll
            for (int j = 0; j < 4; ++j)
                myT[(lg * 4 + j) * LDS_PAD + 16 * c + lr] =
                    (_Float16)lrelu(acc[c][j] + b1c[c]);
        half8 H0 = *(const half8*)(myT + lr * LDS_PAD + lg * 8);
        half8 H1 = *(const half8*)(myT + lr * LDS_PAD + 32 + lg * 8);
#pragma unroll
        for (int c = 0; c < 4; ++c) {
            acc[c] = (f32x4){0.f, 0.f, 0.f, 0.f};
            acc[c] = __builtin_amdgcn_mfma_f32_16x16x32_f16(H0, B2[0][c], acc[c], 0, 0, 0);
            acc[c] = __builtin_amdgcn_mfma_f32_16x16x32_f16(H1, B2[1][c], acc[c], 0, 0, 0);
        }
#pragma unroll
        for (int c = 0; c < 4; ++c)
#pragma unroll
            for (int j = 0; j < 4; ++j)
                myT[(lg * 4 + j) * LDS_PAD + 16 * c + lr] =
                    (_Float16)lrelu(lrelu(acc[c][j] + b2c[c]));
#pragma unroll
        for (int q = 0; q < 2; ++q) {
            half8 o = *(const half8*)(myT + lr * LDS_PAD + (lg + 4 * q) * 8);
            *(half8*)(Hout + (row0 + lr) * DIM + (lg + 4 * q) * 8) = o;
        }
    }
}

// ======================= readout + classifier =======================
__global__ void __launch_bounds__(512) readout_f16_kernel(const _Float16* __restrict__ H,
                                                          const int* __restrict__ gid,
                                                          float* __restrict__ em, int N) {
    __shared__ float sAcc[N_GRAPHS * DIM];
    int tid = threadIdx.x;
    for (int i = tid; i < N_GRAPHS * DIM; i += 512) sAcc[i] = 0.f;
    __syncthreads();
    int lane = tid & 63, wave = tid >> 6;
    int chunk = (N + gridDim.x - 1) / gridDim.x;
    int beg = blockIdx.x * chunk;
    int end = beg + chunk; if (end > N) end = N;
    int n0 = beg + wave * 4;
    for (; n0 + 3 < end; n0 += 32) {   // 8 waves * 4 nodes
        int g0 = gid[n0], g1 = gid[n0 + 1], g2 = gid[n0 + 2], g3 = gid[n0 + 3];
        float v0 = (float)H[(size_t)(n0    ) * DIM + lane];
        float v1 = (float)H[(size_t)(n0 + 1) * DIM + lane];
        float v2 = (float)H[(size_t)(n0 + 2) * DIM + lane];
        float v3 = (float)H[(size_t)(n0 + 3) * DIM + lane];
        atomicAdd(&sAcc[g0 * DIM + lane], v0);
        atomicAdd(&sAcc[g1 * DIM + lane], v1);
        atomicAdd(&sAcc[g2 * DIM + lane], v2);
        atomicAdd(&sAcc[g3 * DIM + lane], v3);
    }
    for (int k = n0; k < end && k < n0 + 4; ++k) {
        int g = gid[k];
        atomicAdd(&sAcc[g * DIM + lane], (float)H[(size_t)k * DIM + lane]);
    }
    __syncthreads();
    for (int i = tid; i < N_GRAPHS * DIM; i += 512) atomicAdd(&em[i], sAcc[i]);
}

__global__ void __launch_bounds__(256) cls_kernel(const float* __restrict__ em,
                                                  const float* __restrict__ W1,
                                                  const float* __restrict__ b1,
                                                  const float* __restrict__ W2,
                                                  const float* __restrict__ b2,
                                                  float* __restrict__ out) {
    __shared__ float sT[N_GRAPHS * DIM];
    __shared__ float sW1[DIM * DIM];
    for (int i = threadIdx.x; i < DIM * DIM; i += 256) sW1[i] = W1[i];
    __syncthreads();
    for (int i = threadIdx.x; i < N_GRAPHS * DIM; i += 256) {
        int g = i >> 6, j = i & 63;
        float acc = b1[j];
#pragma unroll
        for (int k = 0; k < DIM; ++k) acc += em[g * DIM + k] * sW1[k * DIM + j];
        sT[i] = lrelu(acc);
    }
    __syncthreads();
    for (int i = threadIdx.x; i < N_GRAPHS * NCLS; i += 256) {
        int g = i / NCLS, c = i % NCLS;
        float acc = b2[c];
#pragma unroll
        for (int k = 0; k < DIM; ++k) acc += sT[g * DIM + k] * W2[k * NCLS + c];
        out[i] = acc;
    }
}

// ======================= fallback (atomic scatter, fp32) ================
__global__ void copy_kernel(const float* __restrict__ x, float* __restrict__ Y, int n4) {
    int i = blockIdx.x * blockDim.x + threadIdx.x;
    if (i < n4) ((float4*)Y)[i] = ((const float4*)x)[i];
}

__global__ void __launch_bounds__(256) scatter_kernel(const float* __restrict__ Y,
                                                      const int* __restrict__ src,
                                                      const int* __restrict__ dst,
                                                      float* __restrict__ agg, int E) {
    int t = blockIdx.x * blockDim.x + threadIdx.x;
    int e = t >> 4;
    if (e >= E) return;
    int f4 = t & 15;
    int s = src[e];
    int d = dst[e];
    float4 v = ((const float4*)(Y + (size_t)s * DIM))[f4];
    float* ap = agg + (size_t)d * DIM + f4 * 4;
    atomicAdd(ap + 0, v.x);
    atomicAdd(ap + 1, v.y);
    atomicAdd(ap + 2, v.z);
    atomicAdd(ap + 3, v.w);
}

__global__ void __launch_bounds__(256) mlp_kernel(float* __restrict__ Y,
                                                  const float* __restrict__ agg,
                                                  const float* __restrict__ W1,
                                                  const float* __restrict__ b1,
                                                  const float* __restrict__ W2,
                                                  const float* __restrict__ b2, int N) {
    __shared__ float sW1[DIM * DIM];
    __shared__ float sW2[DIM * DIM];
    __shared__ float sb1[DIM];
    __shared__ float sb2[DIM];
    int tid = threadIdx.x;
    for (int i = tid; i < DIM * DIM; i += 256) { sW1[i] = W1[i]; sW2[i] = W2[i]; }
    if (tid < DIM) { sb1[tid] = b1[tid]; sb2[tid] = b2[tid]; }
    __syncthreads();
    int wave = tid >> 6, lane = tid & 63;
    int base = blockIdx.x * 64;
    for (int r = wave; r < 64; r += 4) {
        int row = base + r;
        if (row >= N) break;
        size_t off = (size_t)row * DIM + lane;
        float h = (1.0f + EPS) * Y[off] + agg[off];
        float acc = sb1[lane];
#pragma unroll
        for (int k = 0; k < DIM; ++k) acc += __shfl(h, k) * sW1[k * DIM + lane];
        acc = lrelu(acc);
        float acc2 = sb2[lane];
#pragma unroll
        for (int k = 0; k < DIM; ++k) acc2 += __shfl(acc, k) * sW2[k * DIM + lane];
        Y[off] = lrelu(lrelu(acc2));
    }
}

__global__ void __launch_bounds__(256) readout_kernel(const float* __restrict__ Y,
                                                      const int* __restrict__ gid,
                                                      float* __restrict__ em, int N) {
    __shared__ float sAcc[N_GRAPHS * DIM];
    for (int i = threadIdx.x; i < N_GRAPHS * DIM; i += 256) sAcc[i] = 0.f;
    __syncthreads();
    int lane = threadIdx.x & 63, wave = threadIdx.x >> 6;
    int stride = gridDim.x * 4;
    for (int n = blockIdx.x * 4 + wave; n < N; n += stride) {
        int g = gid[n];
        atomicAdd(&sAcc[g * DIM + lane], Y[(size_t)n * DIM + lane]);
    }
    __syncthreads();
    for (int i = threadIdx.x; i < N_GRAPHS * DIM; i += 256) atomicAdd(&em[i], sAcc[i]);
}

extern "C" void kernel_launch(void* const* d_in, const int* in_sizes, int n_in,
                              void* d_out, int out_size, void* d_ws, size_t ws_size,
                              hipStream_t stream) {
    const float* x       = (const float*)d_in[0];
    const int*   src     = (const int*)d_in[1];
    const int*   dst     = (const int*)d_in[2];
    const int*   gid     = (const int*)d_in[3];
    const float* mlp0_W1 = (const float*)d_in[4];
    const float* mlp0_b1 = (const float*)d_in[5];
    const float* mlp0_W2 = (const float*)d_in[6];
    const float* mlp0_b2 = (const float*)d_in[7];
    const float* mlps_W1 = (const float*)d_in[8];
    const float* mlps_b1 = (const float*)d_in[9];
    const float* mlps_W2 = (const float*)d_in[10];
    const float* mlps_b2 = (const float*)d_in[11];
    const float* cls_W1  = (const float*)d_in[12];
    const float* cls_b1  = (const float*)d_in[13];
    const float* cls_W2  = (const float*)d_in[14];
    const float* cls_b2  = (const float*)d_in[15];
    float* out = (float*)d_out;

    const size_t szH  = (size_t)N_NODES * DIM * sizeof(_Float16);  // 12.8 MB
    const size_t szY  = (size_t)N_NODES * DIM * sizeof(float);     // 25.6 MB
    const size_t szEm = (size_t)N_GRAPHS * DIM * sizeof(float);
    const size_t szRp = (size_t)(N_NODES + 16) * sizeof(int);
    const size_t szE  = (size_t)N_EDGES * sizeof(int);             // 12.8 MB
    const size_t szT  = 512 * sizeof(int);
    const size_t szWf = 6 * 4096 * sizeof(_Float16);               // 48 KB
    const size_t need = 4 * szH + szE + szEm + szRp + 3 * szT + szWf;  // ~64.7 MB

    const float* roundB1[3] = {mlp0_b1, mlps_b1, mlps_b1 + DIM};
    const float* roundB2[3] = {mlp0_b2, mlps_b2, mlps_b2 + DIM};

    if (ws_size >= need) {
        char* w = (char*)d_ws;
        char* slabU   = w;                w += szH;   // ssrcEnc / Hx
        _Float16* Ha  = (_Float16*)w;     w += szH;
        _Float16* Hb  = (_Float16*)w;     w += szH;
        _Float16* aggH= (_Float16*)w;     w += szH;
        int*  ssrc    = (int*)w;          w += szE;
        float* em     = (float*)w;        w += szEm;
        int*  rowptr  = (int*)w;          w += szRp;
        int*  tileS   = (int*)w;          w += szT;
        int*  tileB   = (int*)w;          w += szT;
        int*  bCur    = (int*)w;          w += szT;
        _Float16* wfrag = (_Float16*)w;   w += szWf;
        int*      ssrcEnc = (int*)slabU;
        _Float16* Hx      = (_Float16*)slabU;

        // --- CSR build ---
        hipMemsetAsync(tileS, 0, szT, stream);
        int aBlocks = (N_EDGES + BIN_CH - 1) / BIN_CH;   // 782
        bcount_kernel<<<aBlocks, 256, 0, stream>>>(dst, tileS, N_EDGES);
        tile_scan_kernel<<<1, 512, 0, stream>>>(tileS, tileB, bCur, rowptr, NBKT);
        binA_kernel<<<aBlocks, 512, 0, stream>>>(src, dst, bCur, ssrcEnc, N_EDGES);
        binB_kernel<<<NBKT, 256, 0, stream>>>(ssrcEnc, tileB, rowptr, ssrc, N_EDGES, NBKT);

        // --- weights -> fp16 fragment layout ---
        wcvt_kernel<<<96, 256, 0, stream>>>(mlp0_W1, mlp0_W2, mlps_W1, mlps_W2, wfrag);

        // --- x -> fp16 (reuses ssrcEnc slab; ordered after binB) ---
        int n4 = N_NODES * DIM / 4;
        cvt_kernel<<<(n4 + 255) / 256, 256, 0, stream>>>(x, Hx, n4);

        // --- rounds: Hx -> Ha -> Hb -> Ha, gather + MFMA MLP ---
        const _Float16* Hin[3]  = {Hx, Ha, Hb};
        _Float16*       Hout[3] = {Ha, Hb, Ha};
        const int nTiles = N_NODES / 16;                  // 6250
        for (int j = 0; j < 3; ++j) {
            gather_kernel<<<4096, 256, 0, stream>>>(Hin[j], aggH, rowptr, ssrc, N_NODES);
            mlp_mfma_kernel<<<MLP_BLOCKS, 256, 0, stream>>>(aggH, Hout[j],
                                                            wfrag + (size_t)(2 * j) * 4096,
                                                            wfrag + (size_t)(2 * j + 1) * 4096,
                                                            roundB1[j], roundB2[j], nTiles);
        }

        hipMemsetAsync(em, 0, szEm, stream);
        readout_f16_kernel<<<RO_BLOCKS, 512, 0, stream>>>(Ha, gid, em, N_NODES);
        cls_kernel<<<1, 256, 0, stream>>>(em, cls_W1, cls_b1, cls_W2, cls_b2, out);
    } else {
        // fallback: atomic-scatter fp32 path (needs 2*szY + szEm)
        const float* roundW1[3] = {mlp0_W1, mlps_W1, mlps_W1 + DIM * DIM};
        const float* roundW2[3] = {mlp0_W2, mlps_W2, mlps_W2 + DIM * DIM};
        float* Y   = (float*)d_ws;
        float* agg = Y + (size_t)N_NODES * DIM;
        float* em  = agg + (size_t)N_NODES * DIM;
        int n4 = N_NODES * DIM / 4;
        copy_kernel<<<(n4 + 255) / 256, 256, 0, stream>>>(x, Y, n4);
        for (int j = 0; j < 3; ++j) {
            hipMemsetAsync(agg, 0, szY, stream);
            long long threads = (long long)N_EDGES * 16;
            int blocks = (int)((threads + 255) / 256);
            scatter_kernel<<<blocks, 256, 0, stream>>>(Y, src, dst, agg, N_EDGES);
            int mb = (N_NODES + 63) / 64;
            mlp_kernel<<<mb, 256, 0, stream>>>(Y, agg, roundW1[j], roundB1[j],
                                               roundW2[j], roundB2[j], N_NODES);
        }
        hipMemsetAsync(em, 0, szEm, stream);
        readout_kernel<<<128, 256, 0, stream>>>(Y, gid, em, N_NODES);
        cls_kernel<<<1, 256, 0, stream>>>(em, cls_W1, cls_b1, cls_W2, cls_b2, out);
    }
}